// Round 18
// baseline (73.414 us; speedup 1.0000x reference)
//
#include <hip/hip_runtime.h>
#include <math.h>

#define KW 11
#define HALO 10
#define TY 32
#define BATCH 32
#define HH 512
#define WW 512
#define OH 502
#define OW 502
#define NSX 8          // 8 strips x 64 cols
#define WPB 4          // independent waves per block (no __syncthreads)
#define NBX 2
#define NBY 16
#define NWAVE (BATCH * NBY * NSX)   // 4096
#define C3V 1.0e-4f
#define SW 80          // staged cols per row (64 + 16 halo), one v2f (a,b) each

typedef float v2f __attribute__((ext_vector_type(2)));

static __device__ __forceinline__ float rfl(float x) {
    return __int_as_float(__builtin_amdgcn_readfirstlane(__float_as_int(x)));
}

// 4 independent waves/block; each wave owns a 64-col strip, 44 rows through
// an 11-slot wave-private LDS ring of interleaved (a,b) rows.
// PAIR-PHASE: each phase processes rows yr0,yr0+1 (2 windows read together,
// two independent h-conv chain groups, fused dual v-conv + 2 epilogues).
// Slots advance by 2 mod 11 -> 11 pair-phases = 22 rows = 1 chunk; all slot
// indices compile-time, no parity swaps. Distance-1-pair (~600 cyc) staging:
//   write rows yr0+2,+3 (loaded last phase) -> load rows yr0+4,+5.
__global__ __launch_bounds__(256) void ssim_strip_kernel(
    const float* __restrict__ in1,
    const float* __restrict__ in2,
    const float* __restrict__ win,
    double* __restrict__ partials)
{
    __shared__ v2f sh[WPB][KW][SW];   // 28160 B

    const int t = threadIdx.x;
    const int wid = t >> 6;
    const int lane = t & 63;
    const int strip = blockIdx.x * WPB + wid;
    const int x0 = strip * 64;
    const int y0 = blockIdx.y * TY;
    const int img = blockIdx.z;

    const int nx = min(64, OW - x0);     // 64, last strip 54
    const int ny = min(TY, OH - y0);     // 32, last y-strip 22

    // separable 1D gaussian; symmetric: g[j] == g[10-j] -> 6 unique splats
    v2f gp[6];
    {
        const float c = sqrtf(win[5 * KW + 5]);
        #pragma unroll
        for (int i = 0; i < 6; ++i) {
            const float w = rfl(win[i * KW + 5] / c);
            gp[i] = (v2f){w, w};
        }
    }
    #define GW(j) gp[(j) <= 5 ? (j) : 10 - (j)]

    const float maskf = (lane < nx) ? 1.f : 0.f;
    const bool stager = lane < 40;                    // 40 lanes x 2 cols = 80
    const int scol = min(x0 + 2 * lane, WW - 2);      // clamped: no OOB
    const float* b1 = in1 + (size_t)img * HH * WW;
    const float* b2 = in2 + (size_t)img * HH * WW;

    v2f* const mysh = &sh[wid][0][0];                 // slot stride = SW v2f

    // single staging set: (va0,vb0)=row even, (va1,vb1)=row odd
    v2f va0, vb0, va1, vb1;

#define LOADR0(q) { const int rq = min(y0 + (q), HH - 1);             \
    va0 = *(const v2f*)(b1 + (size_t)rq * WW + scol);                 \
    vb0 = *(const v2f*)(b2 + (size_t)rq * WW + scol); }
#define LOADR1(q) { const int rq = min(y0 + (q), HH - 1);             \
    va1 = *(const v2f*)(b1 + (size_t)rq * WW + scol);                 \
    vb1 = *(const v2f*)(b2 + (size_t)rq * WW + scol); }
#define WRITE0(slot) { if (stager)                                     \
    *(float4*)&mysh[(slot) * SW + 2 * lane] =                          \
        make_float4(va0.x, vb0.x, va0.y, vb0.y); }
#define WRITE1(slot) { if (stager)                                     \
    *(float4*)&mysh[(slot) * SW + 2 * lane] =                          \
        make_float4(va1.x, vb1.x, va1.y, vb1.y); }
#define RDW(slot, Wa) { const v2f* rp = mysh + (slot) * SW + lane;     \
    _Pragma("unroll") for (int j = 0; j < KW; ++j) Wa[j] = rp[j]; }

    // vertical accumulators: (a,b) packed, (aa,bb) packed, ab scalar
    v2f accab[KW], accsq[KW];
    float acc4[KW];
    #pragma unroll
    for (int i = 0; i < KW; ++i) {
        accab[i] = (v2f){0.f, 0.f}; accsq[i] = (v2f){0.f, 0.f}; acc4[i] = 0.f;
    }

    v2f W0[KW], W1[KW];
    double tsum = 0.0;

    // prologue: rows 0,1 staged; rows 2,3 in staging regs
    LOADR0(0); LOADR1(1);
    WRITE0(0); WRITE1(1);
    LOADR0(2); LOADR1(3);

#define HCONV(Wa, hab, hsq, h4) {                                       \
    _Pragma("unroll")                                                   \
    for (int j = 0; j < KW; ++j) {                                      \
        const v2f ab = Wa[j];                                           \
        const v2f g = GW(j);                                            \
        const v2f gab = g * ab;                                         \
        hab = __builtin_elementwise_fma(g, ab, hab);                    \
        hsq = __builtin_elementwise_fma(gab, ab, hsq);                  \
        h4 = fmaf(gab.x, ab.y, h4);                                     \
    } }

#define EPI(r, orow) {                                                  \
    const v2f mu = accab[r];                                            \
    const v2f sq = __builtin_elementwise_fma(-mu, mu, accsq[r]);        \
    const float s12 = fmaf(-mu.x, mu.y, acc4[r]);                       \
    const float den = __builtin_amdgcn_sqrtf(fabsf(sq.x * sq.y)) + C3V; \
    const float s = (s12 + C3V) * __builtin_amdgcn_rcpf(den);           \
    const float m = ((orow) < ny) ? maskf : 0.f;                        \
    csum = fmaf(s, m, csum);                                            \
}

#define PP(pp) {                                                        \
    const int yr0 = cbase + 2 * (pp);                                   \
    /* 1) read both windows (slots written last phase) */               \
    RDW((2 * (pp)) % KW, W0);                                           \
    RDW((2 * (pp) + 1) % KW, W1);                                       \
    /* 2) stage rows yr0+2, yr0+3 (loaded last phase) */                \
    WRITE0((2 * (pp) + 2) % KW);                                        \
    WRITE1((2 * (pp) + 3) % KW);                                        \
    /* 3) load rows yr0+4, yr0+5 into the freed regs */                 \
    LOADR0(yr0 + 4);                                                    \
    LOADR1(yr0 + 5);                                                    \
    __builtin_amdgcn_s_setprio(1);                                      \
    /* 4) two independent h-conv groups (6 parallel fma chains) */      \
    v2f habA = (v2f){0.f, 0.f}, hsqA = (v2f){0.f, 0.f};                 \
    v2f habB = (v2f){0.f, 0.f}, hsqB = (v2f){0.f, 0.f};                 \
    float h4A = 0.f, h4B = 0.f;                                         \
    HCONV(W0, habA, hsqA, h4A);                                         \
    HCONV(W1, habB, hsqB, h4B);                                         \
    /* 5) fused dual v-conv; slot j -> register (j + se) % 11 */        \
    _Pragma("unroll")                                                   \
    for (int r = 0; r < KW; ++r) {                                      \
        const int je = (r - (2 * (pp)) % KW + KW) % KW;                 \
        /* row-even tap: weight g[10-je]; je==10 is first tap */        \
        {                                                               \
            const v2f g = GW(10 - je);                                  \
            if (je == 10) {                                             \
                accab[r] = g * habA; accsq[r] = g * hsqA;               \
                acc4[r] = g.x * h4A;                                    \
            } else {                                                    \
                accab[r] = __builtin_elementwise_fma(g, habA, accab[r]); \
                accsq[r] = __builtin_elementwise_fma(g, hsqA, accsq[r]); \
                acc4[r] = fmaf(g.x, h4A, acc4[r]);                      \
            }                                                           \
        }                                                               \
        if (je == 0) {                                                  \
            /* even output retires, then odd row's FIRST tap overwrites */ \
            if (yr0 >= HALO) EPI(r, yr0 - HALO);                        \
            const v2f g = GW(0);                                        \
            accab[r] = g * habB; accsq[r] = g * hsqB;                   \
            acc4[r] = g.x * h4B;                                        \
        } else {                                                        \
            const int jo = je - 1;                                      \
            const v2f g = GW(10 - jo);                                  \
            accab[r] = __builtin_elementwise_fma(g, habB, accab[r]);    \
            accsq[r] = __builtin_elementwise_fma(g, hsqB, accsq[r]);    \
            acc4[r] = fmaf(g.x, h4B, acc4[r]);                          \
            if (je == 1 && yr0 >= HALO) EPI(r, yr0 - HALO + 1);         \
        }                                                               \
    }                                                                   \
    __builtin_amdgcn_s_setprio(0);                                      \
}

    for (int c = 0; c < 2; ++c) {        // 2 chunks x 22 rows = 44 rows
        const int cbase = c * 22;
        float csum = 0.f;
        PP(0) PP(1) PP(2) PP(3) PP(4) PP(5)
        PP(6) PP(7) PP(8) PP(9) PP(10)
        tsum += (double)csum;
    }
#undef PP
#undef EPI
#undef HCONV
#undef LOADR0
#undef LOADR1
#undef WRITE0
#undef WRITE1
#undef RDW
#undef GW

    // per-wave deterministic reduction
    #pragma unroll
    for (int off = 32; off > 0; off >>= 1)
        tsum += __shfl_down(tsum, off, 64);
    if (lane == 0) {
        const int bid = (img * NBY + blockIdx.y) * NSX + strip;
        partials[bid] = tsum;
    }
}

// deterministic final reduce of the 4096 wave partials -> mean
__global__ __launch_bounds__(256) void ssim_reduce_kernel(
    const double* __restrict__ partials, float* __restrict__ out)
{
    __shared__ double sred[4];
    double s = 0.0;
    for (int i = threadIdx.x; i < NWAVE; i += 256) s += partials[i];
    #pragma unroll
    for (int off = 32; off > 0; off >>= 1)
        s += __shfl_down(s, off, 64);
    const int wid = threadIdx.x >> 6;
    const int lane = threadIdx.x & 63;
    if (lane == 0) sred[wid] = s;
    __syncthreads();
    if (threadIdx.x == 0) {
        const double total = sred[0] + sred[1] + sred[2] + sred[3];
        out[0] = (float)(total / ((double)BATCH * OH * OW));
    }
}

extern "C" void kernel_launch(void* const* d_in, const int* in_sizes, int n_in,
                              void* d_out, int out_size, void* d_ws, size_t ws_size,
                              hipStream_t stream) {
    const float* in1 = (const float*)d_in[0];
    const float* in2 = (const float*)d_in[1];
    const float* win = (const float*)d_in[2];
    float* out = (float*)d_out;
    double* partials = (double*)d_ws;   // 4096 doubles = 32 KB

    dim3 grid(NBX, NBY, BATCH);
    dim3 block(WPB * 64);
    ssim_strip_kernel<<<grid, block, 0, stream>>>(in1, in2, win, partials);
    ssim_reduce_kernel<<<1, 256, 0, stream>>>(partials, out);
}

// Round 19
// 46.862 us; speedup vs baseline: 1.5666x; 1.5666x over previous
//
#include <hip/hip_runtime.h>
#include <math.h>

#define KW 11
#define HALO 10
#define TY 32
#define BATCH 32
#define HH 512
#define WW 512
#define OH 502
#define OW 502
#define NSX 8          // 8 strips x 64 cols
#define WPB 2          // independent waves per block (no __syncthreads)
#define NBX 4
#define NBY 16
#define NWAVE (BATCH * NBY * NSX)   // 4096
#define C3V 1.0e-4f
#define SW 80          // staged cols per row (64 + 16 halo), one v2f (a,b) each

typedef float v2f __attribute__((ext_vector_type(2)));

static __device__ __forceinline__ float rfl(float x) {
    return __int_as_float(__builtin_amdgcn_readfirstlane(__float_as_int(x)));
}

// Best verified configuration (R13, 47.0 us):
// 2 independent waves/block; each wave owns a 64-col strip, 44 rows through
// an 11-slot wave-private LDS ring of interleaved (a,b) rows.
// Phase body (consume-then-refill) + distance-2 global->LDS staging via dual
// register sets (the one pipelining change that measurably paid):
//   phase p (row yr): 1) h-conv from W (row yr)
//                     2) ds_write row yr+1 -> slot p+1 (load is 2 phases old)
//                     3) ds_read slot p+1 -> W
//                     4) global load row yr+3 into the freed set
//                     5) v-conv (register-rotated) + fused epilogue
// Set parity compile-time in the 11-phase unroll; sets swap at chunk end.
__global__ __launch_bounds__(128) void ssim_strip_kernel(
    const float* __restrict__ in1,
    const float* __restrict__ in2,
    const float* __restrict__ win,
    double* __restrict__ partials)
{
    __shared__ v2f sh[WPB][KW][SW];   // 14080 B

    const int t = threadIdx.x;
    const int wid = t >> 6;
    const int lane = t & 63;
    const int strip = blockIdx.x * WPB + wid;
    const int x0 = strip * 64;
    const int y0 = blockIdx.y * TY;
    const int img = blockIdx.z;

    const int nx = min(64, OW - x0);     // 64, last strip 54
    const int ny = min(TY, OH - y0);     // 32, last y-strip 22

    // separable 1D gaussian; symmetric: g[j] == g[10-j] -> 6 unique splats
    v2f gp[6];
    {
        const float c = sqrtf(win[5 * KW + 5]);
        #pragma unroll
        for (int i = 0; i < 6; ++i) {
            const float w = rfl(win[i * KW + 5] / c);
            gp[i] = (v2f){w, w};
        }
    }
    #define GW(j) gp[(j) <= 5 ? (j) : 10 - (j)]

    const float maskf = (lane < nx) ? 1.f : 0.f;
    const bool stager = lane < 40;                    // 40 lanes x 2 cols = 80
    const int scol = min(x0 + 2 * lane, WW - 2);      // clamped: no OOB
    const float* b1 = in1 + (size_t)img * HH * WW;
    const float* b2 = in2 + (size_t)img * HH * WW;

    v2f* const mysh = &sh[wid][0][0];                 // slot stride = SW v2f

    // dual staging sets: at phase p (even->A, odd->B) the set holds row yr+1
    v2f vaA, vbA, vaB, vbB;

#define LOADR_A(q) { const int rq = min(y0 + (q), HH - 1);            \
    vaA = *(const v2f*)(b1 + (size_t)rq * WW + scol);                 \
    vbA = *(const v2f*)(b2 + (size_t)rq * WW + scol); }
#define LOADR_B(q) { const int rq = min(y0 + (q), HH - 1);            \
    vaB = *(const v2f*)(b1 + (size_t)rq * WW + scol);                 \
    vbB = *(const v2f*)(b2 + (size_t)rq * WW + scol); }
#define WRITES_A(slot) { if (stager)                                   \
    *(float4*)&mysh[(slot) * SW + 2 * lane] =                          \
        make_float4(vaA.x, vbA.x, vaA.y, vbA.y); }
#define WRITES_B(slot) { if (stager)                                   \
    *(float4*)&mysh[(slot) * SW + 2 * lane] =                          \
        make_float4(vaB.x, vbB.x, vaB.y, vbB.y); }
#define RDWIN(slot) { const v2f* rp = mysh + (slot) * SW + lane;       \
    _Pragma("unroll") for (int j = 0; j < KW; ++j) W[j] = rp[j]; }

    // vertical accumulators: (a,b) packed, (aa,bb) packed, ab scalar
    v2f accab[KW], accsq[KW];
    float acc4[KW];
    #pragma unroll
    for (int i = 0; i < KW; ++i) {
        accab[i] = (v2f){0.f, 0.f}; accsq[i] = (v2f){0.f, 0.f}; acc4[i] = 0.f;
    }

    v2f W[KW];
    double tsum = 0.0;

    // prologue: row 0 staged + window loaded; row 1 -> set A, row 2 -> set B
    LOADR_A(0);
    WRITES_A(0);
    RDWIN(0);
    LOADR_A(1);
    LOADR_B(2);

#define PHASE(p, S) {                                                   \
    const int yr = cbase + (p);                                         \
    /* 1) horizontal 11-tap conv from W (row yr), packed channels */    \
    v2f hab = (v2f){0.f, 0.f}, hsq = (v2f){0.f, 0.f};                   \
    float h4 = 0.f;                                                     \
    _Pragma("unroll")                                                   \
    for (int j = 0; j < KW; ++j) {                                      \
        const v2f ab = W[j];                                            \
        const v2f g = GW(j);                                            \
        const v2f gab = g * ab;                                         \
        hab = __builtin_elementwise_fma(g, ab, hab);                    \
        hsq = __builtin_elementwise_fma(gab, ab, hsq);                  \
        h4 = fmaf(gab.x, ab.y, h4);                                     \
    }                                                                   \
    /* 2) stage row yr+1 (loaded 2 phases ago) into slot p+1 */         \
    WRITES_##S(((p) + 1) % KW);                                         \
    /* 3) refill W with row yr+1's window */                            \
    RDWIN(((p) + 1) % KW);                                              \
    /* 4) reload freed set with row yr+3 */                             \
    LOADR_##S(yr + 3);                                                  \
    /* 5) vertical accumulate: slot j -> register (j+p)%11; slot 10 */  \
    /*    is the first tap -> overwrite (no reset) */                   \
    _Pragma("unroll")                                                   \
    for (int r = 0; r < KW; ++r) {                                      \
        const int j = (r - (p) + KW) % KW;                              \
        const v2f g = GW(10 - j);                                       \
        if (j == 10) {                                                  \
            accab[r] = g * hab;                                         \
            accsq[r] = g * hsq;                                         \
            acc4[r] = g.x * h4;                                         \
        } else {                                                        \
            accab[r] = __builtin_elementwise_fma(g, hab, accab[r]);     \
            accsq[r] = __builtin_elementwise_fma(g, hsq, accsq[r]);     \
            acc4[r] = fmaf(g.x, h4, acc4[r]);                           \
        }                                                               \
    }                                                                   \
    /* 6) register p completes -> output row yr-10 (uniform branch) */  \
    if (yr >= HALO) {                                                   \
        const v2f mu = accab[(p)];                                      \
        const v2f sq = __builtin_elementwise_fma(-mu, mu, accsq[(p)]);  \
        const float s12 = fmaf(-mu.x, mu.y, acc4[(p)]);                 \
        const float den = __builtin_amdgcn_sqrtf(fabsf(sq.x * sq.y)) + C3V; \
        const float s = (s12 + C3V) * __builtin_amdgcn_rcpf(den);       \
        const float m = ((yr - HALO) < ny) ? maskf : 0.f;               \
        csum = fmaf(s, m, csum);                                        \
    }                                                                   \
}

    for (int c = 0; c < 4; ++c) {        // 44 rows total, fixed
        const int cbase = c * KW;
        float csum = 0.f;
        PHASE(0, A) PHASE(1, B) PHASE(2, A) PHASE(3, B) PHASE(4, A)
        PHASE(5, B) PHASE(6, A) PHASE(7, B) PHASE(8, A) PHASE(9, B)
        PHASE(10, A)
        tsum += (double)csum;
        // 11 phases flips parity: swap sets so "even phase -> A" stays true
        { v2f tmp;
          tmp = vaA; vaA = vaB; vaB = tmp;
          tmp = vbA; vbA = vbB; vbB = tmp; }
    }
#undef PHASE
#undef LOADR_A
#undef LOADR_B
#undef WRITES_A
#undef WRITES_B
#undef RDWIN
#undef GW

    // per-wave deterministic reduction
    #pragma unroll
    for (int off = 32; off > 0; off >>= 1)
        tsum += __shfl_down(tsum, off, 64);
    if (lane == 0) {
        const int bid = (img * NBY + blockIdx.y) * NSX + strip;
        partials[bid] = tsum;
    }
}

// deterministic final reduce of the 4096 wave partials -> mean
__global__ __launch_bounds__(256) void ssim_reduce_kernel(
    const double* __restrict__ partials, float* __restrict__ out)
{
    __shared__ double sred[4];
    double s = 0.0;
    for (int i = threadIdx.x; i < NWAVE; i += 256) s += partials[i];
    #pragma unroll
    for (int off = 32; off > 0; off >>= 1)
        s += __shfl_down(s, off, 64);
    const int wid = threadIdx.x >> 6;
    const int lane = threadIdx.x & 63;
    if (lane == 0) sred[wid] = s;
    __syncthreads();
    if (threadIdx.x == 0) {
        const double total = sred[0] + sred[1] + sred[2] + sred[3];
        out[0] = (float)(total / ((double)BATCH * OH * OW));
    }
}

extern "C" void kernel_launch(void* const* d_in, const int* in_sizes, int n_in,
                              void* d_out, int out_size, void* d_ws, size_t ws_size,
                              hipStream_t stream) {
    const float* in1 = (const float*)d_in[0];
    const float* in2 = (const float*)d_in[1];
    const float* win = (const float*)d_in[2];
    float* out = (float*)d_out;
    double* partials = (double*)d_ws;   // 4096 doubles = 32 KB

    dim3 grid(NBX, NBY, BATCH);
    dim3 block(WPB * 64);
    ssim_strip_kernel<<<grid, block, 0, stream>>>(in1, in2, win, partials);
    ssim_reduce_kernel<<<1, 256, 0, stream>>>(partials, out);
}